// Round 3
// baseline (807.480 us; speedup 1.0000x reference)
//
#include <hip/hip_runtime.h>
#include <hip/hip_bf16.h>

typedef unsigned short u16;
typedef unsigned int   u32;
using bf16x8 = __attribute__((ext_vector_type(8))) short;
using f32x4  = __attribute__((ext_vector_type(4))) float;

#define AS1 __attribute__((address_space(1)))
#define AS3 __attribute__((address_space(3)))

static constexpr int S_   = 1024;
static constexpr int D_   = 4096;
static constexpr int H_   = 32;
static constexpr int KVH_ = 8;
static constexpr int HD_  = 128;
static constexpr int NQKV = H_*HD_ + 2*KVH_*HD_;   // 6144

__device__ __forceinline__ u16 f2bf(float f) {
  union { float f; u32 u; } v; v.f = f;
  u32 r = v.u + 0x7FFFu + ((v.u >> 16) & 1u);      // RTNE
  return (u16)(r >> 16);
}

// ---------------- x f32 -> bf16 ----------------
__global__ void k_convert(const float* __restrict__ src, u16* __restrict__ dst, int n4) {
  int i = blockIdx.x * blockDim.x + threadIdx.x;
  if (i >= n4) return;
  float4 v = ((const float4*)src)[i];
  ushort4 o;
  o.x = f2bf(v.x); o.y = f2bf(v.y); o.z = f2bf(v.z); o.w = f2bf(v.w);
  ((ushort4*)dst)[i] = o;
}

// ---------------- W [K][N] f32 -> Wt [N][K] bf16 ----------------
__global__ void k_transpose_w(const float* __restrict__ src, u16* __restrict__ dst,
                              int K, int N) {
  __shared__ float t[32][33];
  int k0 = blockIdx.y * 32, n0 = blockIdx.x * 32;
  int tx = threadIdx.x, ty = threadIdx.y;           // (32,8)
#pragma unroll
  for (int i = 0; i < 4; ++i)
    t[ty + i*8][tx] = src[(size_t)(k0 + ty + i*8) * N + n0 + tx];
  __syncthreads();
#pragma unroll
  for (int i = 0; i < 4; ++i)
    dst[(size_t)(n0 + ty + i*8) * K + k0 + tx] = f2bf(t[tx][ty + i*8]);
}

// ---------------- V [BG][S][HD] bf16 -> Vt [BG][HD][S] bf16 ----------------
__global__ void k_transpose_v(const u16* __restrict__ src, u16* __restrict__ dst) {
  __shared__ u16 t[32][33];
  int bg = blockIdx.z;
  int s0 = blockIdx.x * 32, h0 = blockIdx.y * 32;
  src += (size_t)bg * S_ * HD_;
  dst += (size_t)bg * S_ * HD_;
  int tx = threadIdx.x, ty = threadIdx.y;
#pragma unroll
  for (int i = 0; i < 4; ++i)
    t[ty + i*8][tx] = src[(size_t)(s0 + ty + i*8) * HD_ + h0 + tx];
  __syncthreads();
#pragma unroll
  for (int i = 0; i < 4; ++i)
    dst[(size_t)(h0 + ty + i*8) * S_ + s0 + tx] = t[tx][ty + i*8];
}

// ---------------- RoPE tables: cos/sin [S][64] f32 ----------------
__global__ void k_rope(const int* __restrict__ sidx, float* __restrict__ cosd,
                       float* __restrict__ sind) {
  int i = blockIdx.x * blockDim.x + threadIdx.x;    // S*64
  int s = i >> 6, d = i & 63;
  float pos  = (float)sidx[s];
  float invf = expf(-0.21586735246819178f * (float)d);  // 1e6^(-d/64)
  float ph   = pos * invf;
  cosd[i] = cosf(ph);
  sind[i] = sinf(ph);
}

// ---------------- 128x128 bf16 GEMM: C[M][N] = A[M][K] * Bt[N][K]^T ----------------
__global__ __launch_bounds__(256) void k_gemm(
    const u16* __restrict__ A, const u16* __restrict__ Bt,
    float* __restrict__ C, int M, int N, int K)
{
  __shared__ char As[16384];
  __shared__ char Bs[16384];
  int tid = threadIdx.x, lane = tid & 63, wid = tid >> 6;
  int l15 = lane & 15, l4 = lane >> 4;
  int m0 = blockIdx.y * 128, n0 = blockIdx.x * 128;
  int wr = wid >> 1, wc = wid & 1;
  f32x4 acc[4][4];
#pragma unroll
  for (int i = 0; i < 4; ++i)
#pragma unroll
    for (int j = 0; j < 4; ++j) acc[i][j] = (f32x4){0.f,0.f,0.f,0.f};

  int arow[4], aslot[4];
#pragma unroll
  for (int q = 0; q < 4; ++q) {
    int o = (wid*4 + q)*1024 + lane*16;
    int row = o >> 7, ss = (o >> 4) & 7;
    arow[q] = row; aslot[q] = ss ^ (row & 7);
  }

  for (int kt = 0; kt < K; kt += 64) {
#pragma unroll
    for (int q = 0; q < 4; ++q) {
      __builtin_amdgcn_global_load_lds(
          (AS1 void*)(A  + (size_t)(m0 + arow[q]) * K + kt + aslot[q]*8),
          (AS3 void*)(As + (wid*4 + q)*1024), 16, 0, 0);
      __builtin_amdgcn_global_load_lds(
          (AS1 void*)(Bt + (size_t)(n0 + arow[q]) * K + kt + aslot[q]*8),
          (AS3 void*)(Bs + (wid*4 + q)*1024), 16, 0, 0);
    }
    __syncthreads();
#pragma unroll
    for (int kk = 0; kk < 2; ++kk) {
      int ks = kk*4 + l4;
      bf16x8 af[4], bfv[4];
#pragma unroll
      for (int i = 0; i < 4; ++i) {
        int row = wr*64 + i*16 + l15;
        af[i] = *(const bf16x8*)(As + row*128 + ((ks ^ (row & 7)) << 4));
      }
#pragma unroll
      for (int j = 0; j < 4; ++j) {
        int row = wc*64 + j*16 + l15;
        bfv[j] = *(const bf16x8*)(Bs + row*128 + ((ks ^ (row & 7)) << 4));
      }
#pragma unroll
      for (int i = 0; i < 4; ++i)
#pragma unroll
        for (int j = 0; j < 4; ++j)
          acc[i][j] = __builtin_amdgcn_mfma_f32_16x16x32_bf16(af[i], bfv[j], acc[i][j], 0, 0, 0);
    }
    __syncthreads();
  }
#pragma unroll
  for (int i = 0; i < 4; ++i)
#pragma unroll
    for (int j = 0; j < 4; ++j) {
      int r0 = m0 + wr*64 + i*16 + l4*4;
      int c0 = n0 + wc*64 + j*16 + l15;
#pragma unroll
      for (int r = 0; r < 4; ++r)
        C[(size_t)(r0 + r) * N + c0] = acc[i][j][r];
    }
}

// ---------------- bias + RoPE + pack to [B][H][S][HD] bf16 ----------------
__global__ void k_pack(const float* __restrict__ Cq,
                       const float* __restrict__ bq, const float* __restrict__ bk,
                       const float* __restrict__ bv,
                       const float* __restrict__ cosd, const float* __restrict__ sind,
                       u16* __restrict__ qb, u16* __restrict__ kb, u16* __restrict__ vb) {
  int t = blockIdx.x;
  int b = t >> 10, s = t & 1023;
  const float* row = Cq + (size_t)t * NQKV;
  const float* cs = cosd + s*64;
  const float* sn = sind + s*64;
  const float qscale = 0.08838834764831845f;  // 1/sqrt(HD)
  for (int c = threadIdx.x; c < H_*HD_; c += blockDim.x) {
    int h = c >> 7, d = c & 127;
    float v = row[c] + bq[c];
    float o;
    if (d < 64) { float p = row[c + 64] + bq[c + 64]; o = v*cs[d]    - p*sn[d]; }
    else        { float p = row[c - 64] + bq[c - 64]; o = v*cs[d-64] + p*sn[d-64]; }
    qb[(((size_t)b*H_ + h)*S_ + s)*HD_ + d] = f2bf(o * qscale);
  }
  for (int c = threadIdx.x; c < KVH_*HD_; c += blockDim.x) {
    int g = c >> 7, d = c & 127;
    float v = row[H_*HD_ + c] + bk[c];
    float o;
    if (d < 64) { float p = row[H_*HD_ + c + 64] + bk[c + 64]; o = v*cs[d]    - p*sn[d]; }
    else        { float p = row[H_*HD_ + c - 64] + bk[c - 64]; o = v*cs[d-64] + p*sn[d-64]; }
    size_t idx = (((size_t)b*KVH_ + g)*S_ + s)*HD_ + d;
    kb[idx] = f2bf(o);
    vb[idx] = f2bf(row[H_*HD_ + KVH_*HD_ + c] + bv[c]);
  }
}

// ---------------- causal GQA flash attention (LDS-staged K/V, dual-tile waves) --------
// grid (8, H, B); block = 4 waves. Wave w owns q-rows [tA*64+w*16, +16) of tile A=t and
// the same rows of tile B=15-t. Per kv step: K/V tile staged to LDS via global_load_lds
// (coalesced, XOR-swizzled via pre-swizzled global source); fragments read once from LDS
// and shared by both tiles' MFMAs. Two barriers/iter (k_gemm structure).
__device__ __forceinline__ void sm_step(f32x4 (&sc)[4], float (&mrow)[4], float (&lrow)[4],
                                        f32x4 (&o)[8], char* Pw, int l15, int l4) {
  float f[4];
#pragma unroll
  for (int r = 0; r < 4; ++r) {
    float mx = fmaxf(fmaxf(sc[0][r], sc[1][r]), fmaxf(sc[2][r], sc[3][r]));
    mx = fmaxf(mx, __shfl_xor(mx, 1));
    mx = fmaxf(mx, __shfl_xor(mx, 2));
    mx = fmaxf(mx, __shfl_xor(mx, 4));
    mx = fmaxf(mx, __shfl_xor(mx, 8));
    float nm = fmaxf(mrow[r], mx);
    f[r] = __expf(mrow[r] - nm);
    mrow[r] = nm;
  }
  float rs[4] = {0.f,0.f,0.f,0.f};
#pragma unroll
  for (int ct = 0; ct < 4; ++ct)
#pragma unroll
    for (int r = 0; r < 4; ++r) {
      float p = __expf(sc[ct][r] - mrow[r]);
      rs[r] += p;
      int row = l4*4 + r, col = ct*16 + l15;
      int byte = row*128 + (((col >> 3) ^ (row & 7)) << 4) + (col & 7)*2;
      *(u16*)(Pw + byte) = f2bf(p);
    }
#pragma unroll
  for (int r = 0; r < 4; ++r) {
    float sum = rs[r];
    sum += __shfl_xor(sum, 1);
    sum += __shfl_xor(sum, 2);
    sum += __shfl_xor(sum, 4);
    sum += __shfl_xor(sum, 8);
    lrow[r] = lrow[r]*f[r] + sum;
  }
#pragma unroll
  for (int n = 0; n < 8; ++n)
#pragma unroll
    for (int r = 0; r < 4; ++r) o[n][r] *= f[r];
}

__device__ __forceinline__ void write_o(const f32x4 (&o)[8], const float (&lrow)[4],
                                        u16* __restrict__ AOh, int qrow0, int l15, int l4) {
#pragma unroll
  for (int n = 0; n < 8; ++n)
#pragma unroll
    for (int r = 0; r < 4; ++r) {
      int srow = qrow0 + l4*4 + r;
      AOh[(size_t)srow * (H_*HD_) + n*16 + l15] = f2bf(o[n][r] / lrow[r]);
    }
}

__global__ __launch_bounds__(256, 2) void k_attn(
    const u16* __restrict__ Q, const u16* __restrict__ Kc,
    const u16* __restrict__ Vt, u16* __restrict__ AO)
{
  int tA = blockIdx.x, tB = 15 - tA;          // paired q-tiles: total work 17 kv-units
  int h = blockIdx.y, b = blockIdx.z, g = h >> 2;
  int tid = threadIdx.x, lane = tid & 63, w = tid >> 6;
  int l15 = lane & 15, l4 = lane >> 4;
  const u16* Qh = Q  + ((size_t)b*H_   + h) * S_ * HD_;
  const u16* Kp = Kc + ((size_t)b*KVH_ + g) * S_ * HD_;
  const u16* Vp = Vt + ((size_t)b*KVH_ + g) * (size_t)HD_ * S_;   // [HD][S]
  u16* AOh = AO + ((size_t)b*S_) * (H_*HD_) + h*HD_;

  __shared__ char Ks[16384];   // [64 rows][16 slots of 16B], slot low3 XOR row&7
  __shared__ char Vs[16384];   // [128 rows][8 slots of 16B], slot XOR row&7
  __shared__ char Ps[16384];   // 4 waves x 2 tiles x 2KB

  char* PwA = Ps + (w*2 + 0)*2048;
  char* PwB = Ps + (w*2 + 1)*2048;

  // staging source offsets (pre-swizzled global source, linear LDS dest)
  int kOff[4], vOff[4];
#pragma unroll
  for (int c = 0; c < 4; ++c) {
    int ci = c*256 + tid;
    int krow = ci >> 4, ks = ci & 15;
    int ksrc = (ks & 8) | ((ks & 7) ^ (krow & 7));
    kOff[c] = krow * HD_ + ksrc * 8;
    int vrow = ci >> 3, vs = ci & 7;
    int vsrc = vs ^ (vrow & 7);
    vOff[c] = vrow * S_ + vsrc * 8;
  }

  // Q fragments for both tiles
  bf16x8 qfA[4], qfB[4];
#pragma unroll
  for (int kc = 0; kc < 4; ++kc) {
    qfA[kc] = *(const bf16x8*)(Qh + (size_t)(tA*64 + w*16 + l15)*HD_ + kc*32 + l4*8);
    qfB[kc] = *(const bf16x8*)(Qh + (size_t)(tB*64 + w*16 + l15)*HD_ + kc*32 + l4*8);
  }

  f32x4 oA[8], oB[8];
#pragma unroll
  for (int n = 0; n < 8; ++n) { oA[n] = (f32x4){0.f,0.f,0.f,0.f}; oB[n] = (f32x4){0.f,0.f,0.f,0.f}; }
  float mA[4] = {-3e38f,-3e38f,-3e38f,-3e38f}, lA[4] = {0.f,0.f,0.f,0.f};
  float mB[4] = {-3e38f,-3e38f,-3e38f,-3e38f}, lB[4] = {0.f,0.f,0.f,0.f};

  for (int kv = 0; kv <= tB; ++kv) {
    int kvb = kv * 64;
    const u16* kSrc = Kp + (size_t)kvb * HD_;
    const u16* vSrc = Vp + kvb;
#pragma unroll
    for (int c = 0; c < 4; ++c) {
      __builtin_amdgcn_global_load_lds((AS1 void*)(kSrc + kOff[c]),
                                       (AS3 void*)(Ks + c*4096 + w*1024), 16, 0, 0);
      __builtin_amdgcn_global_load_lds((AS1 void*)(vSrc + vOff[c]),
                                       (AS3 void*)(Vs + c*4096 + w*1024), 16, 0, 0);
    }
    __syncthreads();   // drains vmcnt: staged tile visible to all waves

    bool aA = (kv <= tA);
    f32x4 scA[4], scB[4];
#pragma unroll
    for (int ct = 0; ct < 4; ++ct) {
      bf16x8 kf[4];
#pragma unroll
      for (int kc = 0; kc < 4; ++kc) {
        int row = ct*16 + l15, s = kc*4 + l4;
        kf[kc] = *(const bf16x8*)(Ks + row*256 + ((((s & 7) ^ (row & 7)) | (s & 8)) << 4));
      }
      f32x4 a4 = (f32x4){0.f,0.f,0.f,0.f}, b4 = (f32x4){0.f,0.f,0.f,0.f};
      if (aA) {
#pragma unroll
        for (int kc = 0; kc < 4; ++kc)
          a4 = __builtin_amdgcn_mfma_f32_16x16x32_bf16(qfA[kc], kf[kc], a4, 0, 0, 0);
      }
#pragma unroll
      for (int kc = 0; kc < 4; ++kc)
        b4 = __builtin_amdgcn_mfma_f32_16x16x32_bf16(qfB[kc], kf[kc], b4, 0, 0, 0);
      scA[ct] = a4; scB[ct] = b4;
    }

    if (kv == tA) {
#pragma unroll
      for (int ct = 0; ct < 4; ++ct)
#pragma unroll
        for (int r = 0; r < 4; ++r) {
          int col = kvb + ct*16 + l15;
          int rw  = tA*64 + w*16 + l4*4 + r;
          if (col > rw) scA[ct][r] = -1e9f;
        }
    }
    if (kv == tB) {
#pragma unroll
      for (int ct = 0; ct < 4; ++ct)
#pragma unroll
        for (int r = 0; r < 4; ++r) {
          int col = kvb + ct*16 + l15;
          int rw  = tB*64 + w*16 + l4*4 + r;
          if (col > rw) scB[ct][r] = -1e9f;
        }
    }

    if (aA) sm_step(scA, mA, lA, oA, PwA, l15, l4);
    sm_step(scB, mB, lB, oB, PwB, l15, l4);

#pragma unroll
    for (int kk = 0; kk < 2; ++kk) {
      int pbyte = l15*128 + (((kk*4 + l4) ^ (l15 & 7)) << 4);
      bf16x8 pfA = {};
      if (aA) pfA = *(const bf16x8*)(PwA + pbyte);
      bf16x8 pfB = *(const bf16x8*)(PwB + pbyte);
#pragma unroll
      for (int n = 0; n < 8; ++n) {
        int row = n*16 + l15, s = kk*4 + l4;
        bf16x8 vf = *(const bf16x8*)(Vs + row*128 + ((s ^ (row & 7)) << 4));
        if (aA) oA[n] = __builtin_amdgcn_mfma_f32_16x16x32_bf16(pfA, vf, oA[n], 0, 0, 0);
        oB[n] = __builtin_amdgcn_mfma_f32_16x16x32_bf16(pfB, vf, oB[n], 0, 0, 0);
      }
    }
    __syncthreads();   // protect Ks/Vs before next stage
  }

  write_o(oA, lA, AOh, tA*64 + w*16, l15, l4);
  write_o(oB, lB, AOh, tB*64 + w*16, l15, l4);
}

extern "C" void kernel_launch(void* const* d_in, const int* in_sizes, int n_in,
                              void* d_out, int out_size, void* d_ws, size_t ws_size,
                              hipStream_t stream) {
  (void)in_sizes; (void)n_in; (void)out_size; (void)ws_size;
  const float* x   = (const float*)d_in[0];
  const int*   sid = (const int*)  d_in[1];
  // d_in[2] = cache (dead), d_in[3] = mask (dead: causal re-derived)
  const float* Wq  = (const float*)d_in[4];
  const float* bq  = (const float*)d_in[5];
  const float* Wk  = (const float*)d_in[6];
  const float* bk  = (const float*)d_in[7];
  const float* Wv  = (const float*)d_in[8];
  const float* bv  = (const float*)d_in[9];
  const float* Wo  = (const float*)d_in[10];
  float* out = (float*)d_out;

  char* ws = (char*)d_ws;
  u16*   xb   = (u16*)  (ws);                    // 16 MB (aliased by AO later)
  u16*   WB   = (u16*)  (ws + 16777216);         // 48 MB  [6144][4096]
  u16*   WoT  = (u16*)  (ws + 67108864);         // 32 MB  [4096][4096]
  float* Cq   = (float*)(ws + 100663296);        // 48 MB  [2048][6144]
  u16*   qb   = (u16*)  (ws + 150994944);        // 16 MB  [B][H][S][HD]
  u16*   kb   = (u16*)  (ws + 167772160);        //  4 MB  [B][KVH][S][HD]
  u16*   vb   = (u16*)  (ws + 171966464);        //  4 MB
  u16*   VT   = (u16*)  (ws + 176160768);        //  4 MB  [B][KVH][HD][S]
  float* cosd = (float*)(ws + 180355072);        // 256 KB
  float* sind = (float*)(ws + 180617216);        // 256 KB (total ~181 MB)
  u16*   AO   = xb;                              // attention output reuses xb

  dim3 tb(32, 8);
  k_convert<<<8192, 256, 0, stream>>>(x, xb, (2048*4096)/4);
  k_transpose_w<<<dim3(128,128), tb, 0, stream>>>(Wq, WB, 4096, 4096);
  k_transpose_w<<<dim3( 32,128), tb, 0, stream>>>(Wk, WB + (size_t)4096*4096, 4096, 1024);
  k_transpose_w<<<dim3( 32,128), tb, 0, stream>>>(Wv, WB + (size_t)5120*4096, 4096, 1024);
  k_transpose_w<<<dim3(128,128), tb, 0, stream>>>(Wo, WoT, 4096, 4096);
  k_rope<<<256, 256, 0, stream>>>(sid, cosd, sind);
  k_gemm<<<dim3(48,16), 256, 0, stream>>>(xb, WB, Cq, 2048, NQKV, 4096);
  k_pack<<<2048, 256, 0, stream>>>(Cq, bq, bk, bv, cosd, sind, qb, kb, vb);
  k_transpose_v<<<dim3(32,4,16), tb, 0, stream>>>(vb, VT);
  k_attn<<<dim3(8,32,2), 256, 0, stream>>>(qb, kb, VT, AO);
  k_gemm<<<dim3(32,16), 256, 0, stream>>>(AO, WoT, out, 2048, 4096, 4096);
}